// Round 3
// baseline (73804.572 us; speedup 1.0000x reference)
//
#include <hip/hip_runtime.h>
#include <math.h>

// LSTM T=32768, B=1, I=128, H=512. Persistent kernel: 32 team WGs x 512 threads.
// R15: R13/R14's XCD-local fast transport was structurally dead (identical
// deterministic error in both rounds => pollers never saw a packet; out==b_eff).
// This round is correct under every hypothesis, fast under the optimistic one:
//   * TEAM BY blockIdx: bid%8==0 (documented round-robin bid->XCD mapping),
//     slot w = bid>>3. No HW_REG_XCC_ID, no tickets, no ctrl block.
//   * DUAL-RAIL publish at DISJOINT addresses:
//       fast rail: plain global_store_dwordx2 -> XCD-local L2, sc0 polls
//       slow rail: __hip_atomic_store AGENT (R12-proven MALL path)
//     Disjoint lines => no L2-eviction/MALL ordering interaction; 8-bit
//     in-band tags make both rails self-validating.
//   * ADAPTIVE POLL: fast rail first; after FT failed iters in a step,
//     escalate that step to agent loads on the slow rail. 3 escalated steps
//     (t>=4) => sticky slow mode. Healthy fast rail = full L2-local win;
//     dead fast rail = one-time ~ms penalty then R12 behavior. Correct always.
//   * t=0 synthesizes h0=0 (wire never read at t=0); tags reject stale data.

#define T_SEQ 32768
#define HID   512
#define INP   128
#define NWG   32    // team size
#define GRID  256   // launched WGs; team = bids {0,8,...,248} -> XCD0
#define NTH   512   // 8 waves; wave0 polls then computes
#define HSL   16    // h elements per WG
#define KW    64    // W_hh weights per thread
#define KX    16    // W_ih weights per thread
#define NPK   256   // packets per parity (2 h each)

typedef unsigned long long u64;
typedef unsigned int u32;

__device__ __forceinline__ float fast_sigmoid(float x) {
    return 1.0f / (1.0f + __expf(-x));
}
__device__ __forceinline__ float fast_tanh(float x) {
    float a = fabsf(x);
    float e = __expf(-2.0f * a);          // underflows to 0 for large a -> r=1
    float r = (1.0f - e) / (1.0f + e);
    return copysignf(r, x);
}

__global__ void __launch_bounds__(NTH, 1) lstm_persist(
    const float* __restrict__ x,
    const float* __restrict__ W_ih,
    const float* __restrict__ W_hh,
    const float* __restrict__ b_ih,
    const float* __restrict__ b_hh,
    const float* __restrict__ W1,
    const float* __restrict__ b1,
    const float* __restrict__ Wout,
    u64* __restrict__ hb_fast,          // 2 x 256 packets (XCD-local rail)
    u64* __restrict__ hb_slow,          // 2 x 256 packets (MALL rail)
    float* __restrict__ out)
{
    const int bid = blockIdx.x;
    if (bid & 7) return;                // team: one block per XCD0 CU
    const int w   = bid >> 3;           // team slot 0..31
    const int tid = threadIdx.x;
    const int wv  = tid >> 6;           // 0..7
    const int l   = tid & 63;
    const int rw  = l >> 3;             // 0..7 = (gate g, elem b)
    const int j   = l & 7;              // K-chunk
    const int g   = rw >> 1;
    const int b   = rw & 1;
    const bool is_out = (w == 0 && wv == 1);   // slot0 wave1 computes out[]

    __shared__ __align__(16) float h_lds[2][HID];   // parity double buffer
    __shared__ u64 gather_lds[8];                   // per-wave packet staging

    // each wave owns elements {16w + 2wv, 16w + 2wv + 1}; 8 rows (4 gates x 2)
    const int grow = g * HID + w * HSL + 2 * wv + b;

    // ---- weights, j-rotated order to match the LDS read schedule ----
    float wr[KW], wi[KX];
#pragma unroll
    for (int kk = 0; kk < 16; ++kk) {
        const int p = (kk + 2 * j) & 15;
        const float4 v4 = *(const float4*)&W_hh[grow * HID + j * KW + 4 * p];
        wr[4 * kk + 0] = v4.x; wr[4 * kk + 1] = v4.y;
        wr[4 * kk + 2] = v4.z; wr[4 * kk + 3] = v4.w;
    }
#pragma unroll
    for (int k = 0; k < KX; k += 4) {
        const float4 v4 = *(const float4*)&W_ih[grow * INP + j * KX + k];
        wi[k] = v4.x; wi[k + 1] = v4.y; wi[k + 2] = v4.z; wi[k + 3] = v4.w;
    }
    float brow = b_ih[grow] + b_hh[grow];

    // out-projection weights (slot0 wave1): lane l covers h indices l + 64*i
    float weff_o[8];
    float be = 0.0f;
#pragma unroll
    for (int i = 0; i < 8; ++i) weff_o[i] = 0.0f;
    if (is_out) {
#pragma unroll
        for (int i = 0; i < 8; ++i) {
            float s = 0.0f;
            for (int p = 0; p < 25; ++p) s += Wout[p] * W1[p * HID + l + 64 * i];
            weff_o[i] = s;
        }
        for (int p = 0; p < 25; ++p) be += b1[p] * Wout[p];
    }
    // pin against in-loop memory clobbers
#pragma unroll
    for (int k = 0; k < KW; ++k) asm volatile("" : "+v"(wr[k]));
#pragma unroll
    for (int k = 0; k < KX; ++k) asm volatile("" : "+v"(wi[k]));
#pragma unroll
    for (int i = 0; i < 8; ++i) asm volatile("" : "+v"(weff_o[i]));
    asm volatile("" : "+v"(brow));
    asm volatile("" : "+v"(be));

    float c = 0.0f;
    float xa[KX];
#pragma unroll
    for (int k = 0; k < KX; ++k) xa[k] = x[j * KX + k];

    bool dead = false;        // safety latch: never hang the device
    bool slowMode = false;    // sticky: fast rail declared dead
    int  slowSteps = 0;       // escalated-step count (t>=4 only)

    for (u32 t = 0; t <= T_SEQ; ++t) {
        if (t == T_SEQ && w != 0) break;   // only slot0 runs the tail iteration

        // ---- x-dot partials for step t (pure VALU; overlaps the poll) ----
        float xd0 = 0.0f, xd1 = 0.0f, xd2 = 0.0f, xd3 = 0.0f;
#pragma unroll
        for (int k = 0; k < KX; k += 4) {
            xd0 += wi[k + 0] * xa[k + 0];
            xd1 += wi[k + 1] * xa[k + 1];
            xd2 += wi[k + 2] * xa[k + 2];
            xd3 += wi[k + 3] * xa[k + 3];
        }
        // xa consumed -> prefetch x_{t+1}. Compute waves: before the barrier
        // (latency hides inside the wait). Poller: after the barrier.
        const int tn = (t + 1 < T_SEQ) ? (int)(t + 1) : (T_SEQ - 1);
        if (wv != 0) {
#pragma unroll
            for (int k = 0; k < KX; k += 4) {
                const float4 x4 = *(const float4*)&x[tn * INP + j * KX + k];
                xa[k + 0] = x4.x; xa[k + 1] = x4.y;
                xa[k + 2] = x4.z; xa[k + 3] = x4.w;
            }
        }

        // ---- wave0 fills h_lds: t=0 synthesizes h0=0; t>=1 polls, fast
        //      rail (sc0, XCD-local L2) with escalation to the slow rail
        //      (agent loads at MALL) ----
        if (wv == 0 && !dead) {
            float2* HL = (float2*)h_lds[t & 1];
            if (t == 0) {
                float2 z; z.x = 0.0f; z.y = 0.0f;
                HL[l +   0] = z;
                HL[l +  64] = z;
                HL[l + 128] = z;
                HL[l + 192] = z;
            } else {
                const int par = (t & 1) * NPK;
                const u64 a0 = (u64)(hb_fast + par + l);
                const u64 a1 = a0 +  64u * sizeof(u64);
                const u64 a2 = a0 + 128u * sizeof(u64);
                const u64 a3 = a0 + 192u * sizeof(u64);
                const u64* PS = hb_slow + par;
                const u32 tLo = t & 15u;
                const u32 tHi = (t >> 4) & 15u;
                const int ft = (t < 4) ? 4096 : 96;   // cold-start headroom
                bool mine = false;
                bool slow = slowMode;
                int it = 0;
                while (true) {
                    if (!mine) {
                        u64 p0, p1, p2, p3;
                        if (!slow) {
                            asm volatile(
                                "global_load_dwordx2 %0, %4, off sc0\n\t"
                                "global_load_dwordx2 %1, %5, off sc0\n\t"
                                "global_load_dwordx2 %2, %6, off sc0\n\t"
                                "global_load_dwordx2 %3, %7, off sc0\n\t"
                                "s_waitcnt vmcnt(0)"
                                : "=&v"(p0), "=&v"(p1), "=&v"(p2), "=&v"(p3)
                                : "v"(a0), "v"(a1), "v"(a2), "v"(a3)
                                : "memory");
                            __builtin_amdgcn_sched_barrier(0);
                        } else {
                            p0 = __hip_atomic_load(PS + l, __ATOMIC_RELAXED,
                                                   __HIP_MEMORY_SCOPE_AGENT);
                            p1 = __hip_atomic_load(PS + l + 64, __ATOMIC_RELAXED,
                                                   __HIP_MEMORY_SCOPE_AGENT);
                            p2 = __hip_atomic_load(PS + l + 128, __ATOMIC_RELAXED,
                                                   __HIP_MEMORY_SCOPE_AGENT);
                            p3 = __hip_atomic_load(PS + l + 192, __ATOMIC_RELAXED,
                                                   __HIP_MEMORY_SCOPE_AGENT);
                        }
                        const bool ok =
                            ((((u32)p0 ^ tLo) & 15u) == 0u) &&
                            ((((u32)(p0 >> 32) ^ tHi) & 15u) == 0u) &&
                            ((((u32)p1 ^ tLo) & 15u) == 0u) &&
                            ((((u32)(p1 >> 32) ^ tHi) & 15u) == 0u) &&
                            ((((u32)p2 ^ tLo) & 15u) == 0u) &&
                            ((((u32)(p2 >> 32) ^ tHi) & 15u) == 0u) &&
                            ((((u32)p3 ^ tLo) & 15u) == 0u) &&
                            ((((u32)(p3 >> 32) ^ tHi) & 15u) == 0u);
                        if (ok) {
                            float2 h0, h1, h2, h3;
                            h0.x = __uint_as_float((u32)p0);
                            h0.y = __uint_as_float((u32)(p0 >> 32));
                            h1.x = __uint_as_float((u32)p1);
                            h1.y = __uint_as_float((u32)(p1 >> 32));
                            h2.x = __uint_as_float((u32)p2);
                            h2.y = __uint_as_float((u32)(p2 >> 32));
                            h3.x = __uint_as_float((u32)p3);
                            h3.y = __uint_as_float((u32)(p3 >> 32));
                            HL[l +   0] = h0;
                            HL[l +  64] = h1;
                            HL[l + 128] = h2;
                            HL[l + 192] = h3;
                            mine = true;
                        }
                    }
                    if (__ballot(mine) == ~0ull) break;
                    ++it;
                    if (it == ft) slow = true;                 // escalate step
                    if (it > (1 << 22)) { dead = true; break; }   // no hang
                }
                if (slow && !slowMode && t >= 4) {
                    if (++slowSteps >= 3) slowMode = true;     // sticky
                }
            }
        }
        __syncthreads();

        if (t < T_SEQ) {
            float a0 = xd0, a1 = xd1, a2 = xd2, a3 = xd3;
            const float4* hl4 = (const float4*)&h_lds[t & 1][j * KW];
#pragma unroll
            for (int kk = 0; kk < 16; ++kk) {
                const int p = (kk + 2 * j) & 15;
                const float4 h4 = hl4[p];
                a0 += wr[4 * kk + 0] * h4.x;
                a1 += wr[4 * kk + 1] * h4.y;
                a2 += wr[4 * kk + 2] * h4.z;
                a3 += wr[4 * kk + 3] * h4.w;
            }
            // poller's x-prefetch (after barrier, overlaps the h-dot)
            if (wv == 0) {
#pragma unroll
                for (int k = 0; k < KX; k += 4) {
                    const float4 x4 = *(const float4*)&x[tn * INP + j * KX + k];
                    xa[k + 0] = x4.x; xa[k + 1] = x4.y;
                    xa[k + 2] = x4.z; xa[k + 3] = x4.w;
                }
            }
            // xor-butterfly over j: every lane holds its row's full sum
            float acc = (a0 + a1) + (a2 + a3);
            acc += __shfl_xor(acc, 1);
            acc += __shfl_xor(acc, 2);
            acc += __shfl_xor(acc, 4);
            acc += brow;
            // gates of element b live at rw = b, b+2, b+4, b+6 (valid l<16)
            const float ig = acc;
            const float fg = __shfl(acc, l + 16);
            const float gg = __shfl(acc, l + 32);
            const float og = __shfl(acc, l + 48);
            const float iv = fast_sigmoid(ig);
            const float fv = fast_sigmoid(fg);
            const float gv = fast_tanh(gg);
            const float ov = fast_sigmoid(og);
            c = fv * c + iv * gv;
            const float hv = ov * fast_tanh(c);
            // stage this wave's packet: 8-bit tag in-band — (t+1)&15 in
            // h_even low nibble, ((t+1)>>4)&15 in h_odd low nibble
            const float hv1 = __shfl(hv, 8);     // element b=1 (lane 8)
            if (l == 0) {
                const u32 b0  = (__float_as_uint(hv)  & ~15u) | ((t + 1) & 15u);
                const u32 b1v = (__float_as_uint(hv1) & ~15u) | (((t + 1) >> 4) & 15u);
                gather_lds[wv] = ((u64)b1v << 32) | (u64)b0;
            }
            __syncthreads();   // barrier B: all 8 packets staged
            // ---- dual-rail coalesced publish: wave0 lanes 0-7 ----
            if (wv == 0 && l < 8) {
                const u64 pkt = gather_lds[l];
                const int idx = ((t + 1) & 1) * NPK + w * 8 + l;
                const u64 adf = (u64)&hb_fast[idx];
                asm volatile("global_store_dwordx2 %0, %1, off"
                             :: "v"(adf), "v"(pkt) : "memory");
                __hip_atomic_store(&hb_slow[idx], pkt,
                                   __ATOMIC_RELAXED, __HIP_MEMORY_SCOPE_AGENT);
            }
        }

        // out[t-1] = dot(h_{t-1}, w_eff) + b_eff — slot0 wave1, after publish
        if (is_out && t >= 1) {
            float pd = 0.0f;
#pragma unroll
            for (int i = 0; i < 8; ++i)
                pd += h_lds[t & 1][l + 64 * i] * weff_o[i];
            pd += __shfl_xor(pd, 1);
            pd += __shfl_xor(pd, 2);
            pd += __shfl_xor(pd, 4);
            pd += __shfl_xor(pd, 8);
            pd += __shfl_xor(pd, 16);
            pd += __shfl_xor(pd, 32);
            if (l == 0) out[t - 1] = pd + be;
        }
    }
}

extern "C" void kernel_launch(void* const* d_in, const int* in_sizes, int n_in,
                              void* d_out, int out_size, void* d_ws, size_t ws_size,
                              hipStream_t stream)
{
    const float* x    = (const float*)d_in[0];
    const float* W_ih = (const float*)d_in[1];
    const float* W_hh = (const float*)d_in[2];
    const float* b_ih = (const float*)d_in[3];
    const float* b_hh = (const float*)d_in[4];
    const float* W1   = (const float*)d_in[5];
    const float* b1   = (const float*)d_in[6];
    const float* Wout = (const float*)d_in[7];
    float* out = (float*)d_out;

    u64* hb_fast = (u64*)d_ws;              // 2 x 256 packets = 4 KB
    u64* hb_slow = hb_fast + 2 * NPK;       // 2 x 256 packets = 4 KB

    // zero both rails (tags reject stale data; t=0 never reads the wire)
    hipMemsetAsync(d_ws, 0, 4 * NPK * sizeof(u64), stream);
    lstm_persist<<<GRID, NTH, 0, stream>>>(x, W_ih, W_hh, b_ih, b_hh, W1, b1,
                                           Wout, hb_fast, hb_slow, out);
}